// Round 5
// baseline (240.405 us; speedup 1.0000x reference)
//
#include <hip/hip_runtime.h>
#include <hip/hip_bf16.h>
#include <stdint.h>

typedef __attribute__((ext_vector_type(4))) float f32x4;
typedef __attribute__((ext_vector_type(8))) __bf16 bf16x8;
typedef __attribute__((ext_vector_type(2))) unsigned int u32x2;
typedef __attribute__((ext_vector_type(4))) unsigned int u32x4;

#define N_NODES 16384
#define F_DIM   64

__device__ inline unsigned cvtpk_bf16(float lo, float hi) {
    unsigned r;
    asm("v_cvt_pk_bf16_f32 %0, %1, %2" : "=v"(r) : "v"(lo), "v"(hi));
    return r;
}

// ---------------------------------------------------------------------------
// Kernel A: h = input @ W (fp32 compute), stored bf16 in MFMA B-frag layout:
// chunk[(kb*4+ct)*64 + l] (16B) = h[kb*32 + (l>>4)*8 + j][ct*16 + (l&15)]
// ---------------------------------------------------------------------------
__global__ __launch_bounds__(256) void dense_h(const float* __restrict__ inp,
                                               const float* __restrict__ W,
                                               short* __restrict__ hpack) {
    __shared__ float in_lds[64][64];
    __shared__ float wt_lds[64][68];
    const int t = threadIdx.x;
    const int blk = blockIdx.x;

#pragma unroll
    for (int i = 0; i < 4; ++i) {
        int n = i * 256 + t; int row = n >> 4; int c = n & 15;
        f32x4 v = *(const f32x4*)(inp + (size_t)(blk * 64 + row) * 64 + c * 4);
        *(f32x4*)(&in_lds[row][c * 4]) = v;
    }
#pragma unroll
    for (int i = 0; i < 4; ++i) {
        int n = i * 256 + t; int k = n >> 4; int c = n & 15;
        f32x4 v = *(const f32x4*)(W + k * 64 + c * 4);
        wt_lds[c * 4 + 0][k] = v.x; wt_lds[c * 4 + 1][k] = v.y;
        wt_lds[c * 4 + 2][k] = v.z; wt_lds[c * 4 + 3][k] = v.w;
    }
    __syncthreads();

#pragma unroll
    for (int cc = 0; cc < 2; ++cc) {
        int c = cc * 256 + t;
        int kbL = c >> 8; int ct = (c >> 6) & 3; int l = c & 63;
        int f  = ct * 16 + (l & 15);
        int r0 = kbL * 32 + (l >> 4) * 8;
        float acc[8] = {0, 0, 0, 0, 0, 0, 0, 0};
        for (int k = 0; k < 64; k += 4) {
            f32x4 wv = *(const f32x4*)(&wt_lds[f][k]);
#pragma unroll
            for (int j = 0; j < 8; ++j) {
                f32x4 iv = *(const f32x4*)(&in_lds[r0 + j][k]);
                acc[j] += iv.x * wv.x + iv.y * wv.y + iv.z * wv.z + iv.w * wv.w;
            }
        }
        u32x4 w4 = {cvtpk_bf16(acc[0], acc[1]), cvtpk_bf16(acc[2], acc[3]),
                    cvtpk_bf16(acc[4], acc[5]), cvtpk_bf16(acc[6], acc[7])};
        int kb = blk * 2 + kbL;
        *(u32x4*)(hpack + ((size_t)(kb * 4 + ct) * 64 + l) * 8) = w4;
    }
}

// ---------------------------------------------------------------------------
// Kernel B: partial[sp] = adj[:, k-range] @ h[k-range, :]
// R0 structure EXACTLY (block-wide coalesced LDS staging, XOR swizzle, raw
// s_barrier + lgkmcnt(0), 16 waves/CU, nsp=4) with one change: A-prefetch
// 2 iterations deep and B issued a full iteration before consume.
// All waits counted: stA waits vmcnt(12); B-consume waits vmcnt(4).
// In-flight HBM bytes/CU ~2x the Little's-law edge (was ~1.0x in R0).
// ---------------------------------------------------------------------------
__global__ __launch_bounds__(256, 4) void spmm_adj(const float* __restrict__ adj,
                                                   const short* __restrict__ hp,
                                                   float* __restrict__ out,
                                                   int kspan) {
    const int rb = blockIdx.x;
    const int sp = blockIdx.y;
    const int k0 = sp * kspan;
    const int iters = kspan >> 6;          // K-step 64; iters even, >= 4
    const int t  = threadIdx.x;
    const int wv = t >> 6;
    const int ln = t & 63;

    __shared__ short At[2][64 * 64];       // bf16, XOR-swizzled, 8KB each

    const size_t rowbase = (size_t)(rb * 64) * N_NODES;
    const int srow = t >> 4;               // staging row within 16-row group
    const int scol = t & 15;               // 16B chunk

    auto ldA = [&](int tt, f32x4* rv) {    // 64x64 fp32 tile, 256B contiguous / 16 lanes
        const float* base = adj + rowbase + (size_t)(k0 + tt * 64);
#pragma unroll
        for (int i = 0; i < 4; ++i) {
            int row = i * 16 + srow;
            rv[i] = __builtin_nontemporal_load(
                (const f32x4*)(base + (size_t)row * N_NODES + scol * 4));
        }
    };
    auto stA = [&](int buf, const f32x4* rv) {
#pragma unroll
        for (int i = 0; i < 4; ++i) {
            int row = i * 16 + srow;
            u32x2 w = {cvtpk_bf16(rv[i].x, rv[i].y), cvtpk_bf16(rv[i].z, rv[i].w)};
            int byte = row * 128 + ((scol * 8) ^ ((row & 7) << 4));
            *(u32x2*)((char*)At[buf] + byte) = w;
        }
    };
    auto ldB = [&](int tt, bf16x8* b) {    // B-frags from packed h (L2-hot)
        const short* h = hp + (size_t)(k0 >> 5) * 2048 + (size_t)tt * 4096 + ln * 8;
#pragma unroll
        for (int ks2 = 0; ks2 < 2; ++ks2)
#pragma unroll
            for (int ct = 0; ct < 4; ++ct)
                b[ks2 * 4 + ct] = *(const bf16x8*)(h + ks2 * 2048 + ct * 512);
    };

    f32x4 acc[4] = {{0,0,0,0},{0,0,0,0},{0,0,0,0},{0,0,0,0}};
    const int abase = (wv * 16 + (ln & 15)) * 128;
    const int aswz  = (ln & 7) << 4;
    const int koff  = (ln >> 4) * 16;

    auto mfmaPhase = [&](int buf, const bf16x8* b) {
#pragma unroll
        for (int ks2 = 0; ks2 < 2; ++ks2) {
            bf16x8 a = *(const bf16x8*)((const char*)At[buf] + abase + ((ks2 * 64 + koff) ^ aswz));
#pragma unroll
            for (int ct = 0; ct < 4; ++ct)
                acc[ct] = __builtin_amdgcn_mfma_f32_16x16x32_bf16(a, b[ks2 * 4 + ct], acc[ct], 0, 0, 0);
        }
    };

    f32x4 rv0[4], rv1[4];
    bf16x8 bb[8];

    // prologue: B(0); A(0); A(1); stage A(0)->buf0
    ldB(0, bb);
    ldA(0, rv0);
    ldA(1, rv1);
    __builtin_amdgcn_sched_barrier(0);
    stA(0, rv0);                           // waits A(0): vmcnt(4) (A(1) in flight)
    asm volatile("s_waitcnt lgkmcnt(0)" ::: "memory");
    __builtin_amdgcn_s_barrier();

    int tt = 0;
    for (; tt < iters - 2; tt += 2) {
        // iter tt (even): compute buf0 = A(tt), bb = B(tt)
        mfmaPhase(0, bb);                  // B-consume: vmcnt(4), counted
        ldB(tt + 1, bb);                   // anti-dep on bb keeps this after MFMAs
        ldA(tt + 2, rv0);                  // rv0 free (A(tt) staged in iter tt-1)
        __builtin_amdgcn_sched_barrier(0); // pin issues before stA's vmcnt wait
        stA(1, rv1);                       // consumes A(tt+1): vmcnt(12), counted
        asm volatile("s_waitcnt lgkmcnt(0)" ::: "memory");
        __builtin_amdgcn_s_barrier();
        // iter tt+1 (odd): compute buf1 = A(tt+1), bb = B(tt+1)
        mfmaPhase(1, bb);
        ldB(tt + 2, bb);
        ldA(tt + 3, rv1);
        __builtin_amdgcn_sched_barrier(0);
        stA(0, rv0);                       // consumes A(tt+2): vmcnt(12)
        asm volatile("s_waitcnt lgkmcnt(0)" ::: "memory");
        __builtin_amdgcn_s_barrier();
    }
    // tail: iters-2, iters-1
    mfmaPhase(0, bb);
    ldB(iters - 1, bb);
    __builtin_amdgcn_sched_barrier(0);
    stA(1, rv1);                           // consumes A(iters-1)
    asm volatile("s_waitcnt lgkmcnt(0)" ::: "memory");
    __builtin_amdgcn_s_barrier();
    mfmaPhase(1, bb);

    // epilogue: C layout col=lane&15, row=(lane>>4)*4+j
    float* o = out + (size_t)sp * ((size_t)N_NODES * F_DIM);
    const int orow0 = rb * 64 + wv * 16 + (ln >> 4) * 4;
    const int col   = ln & 15;
#pragma unroll
    for (int ct = 0; ct < 4; ++ct)
#pragma unroll
        for (int j = 0; j < 4; ++j)
            o[(size_t)(orow0 + j) * F_DIM + ct * 16 + col] = acc[ct][j];
}

// ---------------------------------------------------------------------------
// Kernel C: out = sum_i partial[i] + bias
// ---------------------------------------------------------------------------
__global__ __launch_bounds__(256) void reduce_add(const float* __restrict__ part,
                                                  const float* __restrict__ bias,
                                                  float* __restrict__ out, int nsp) {
    int g = blockIdx.x * 256 + threadIdx.x;
    f32x4 s = {0, 0, 0, 0};
    for (int i = 0; i < nsp; ++i)
        s += *(const f32x4*)(part + (size_t)i * ((size_t)N_NODES * F_DIM) + (size_t)g * 4);
    f32x4 bv = *(const f32x4*)(bias + ((g * 4) & 63));
    *(f32x4*)(out + (size_t)g * 4) = s + bv;
}

extern "C" void kernel_launch(void* const* d_in, const int* in_sizes, int n_in,
                              void* d_out, int out_size, void* d_ws, size_t ws_size,
                              hipStream_t stream) {
    const float* inp = (const float*)d_in[0];
    const float* adj = (const float*)d_in[1];
    const float* W   = (const float*)d_in[2];
    const float* b   = (const float*)d_in[3];
    float* out = (float*)d_out;

    char*  ws = (char*)d_ws;
    const size_t HP = (size_t)N_NODES * F_DIM * sizeof(short);   // 2 MB packed bf16 h
    short* hpack = (short*)ws;
    float* partial = (float*)(ws + HP);
    const size_t P1 = (size_t)N_NODES * F_DIM * sizeof(float);   // 4 MB per partial

    dense_h<<<N_NODES / 64, 256, 0, stream>>>(inp, W, hpack);

    if (ws_size >= HP + 4 * P1) {
        dim3 g(N_NODES / 64, 4);           // 1024 blocks = one residency round
        spmm_adj<<<g, 256, 0, stream>>>(adj, hpack, partial, N_NODES / 4);
        reduce_add<<<(N_NODES * F_DIM) / 1024, 256, 0, stream>>>(partial, b, out, 4);
    } else if (ws_size >= HP + P1) {
        dim3 g(N_NODES / 64, 1);
        spmm_adj<<<g, 256, 0, stream>>>(adj, hpack, partial, N_NODES);
        reduce_add<<<(N_NODES * F_DIM) / 1024, 256, 0, stream>>>(partial, b, out, 1);
    } else {
        dim3 g(N_NODES / 64, 1);
        spmm_adj<<<g, 256, 0, stream>>>(adj, hpack, out, N_NODES);
        reduce_add<<<(N_NODES * F_DIM) / 1024, 256, 0, stream>>>(out, b, out, 1);
    }
}

// Round 6
// 207.312 us; speedup vs baseline: 1.1596x; 1.1596x over previous
//
#include <hip/hip_runtime.h>
#include <hip/hip_bf16.h>
#include <stdint.h>

typedef __attribute__((ext_vector_type(4))) float f32x4;
typedef __attribute__((ext_vector_type(8))) __bf16 bf16x8;
typedef __attribute__((ext_vector_type(2))) unsigned int u32x2;
typedef __attribute__((ext_vector_type(4))) unsigned int u32x4;

#define N_NODES 16384
#define F_DIM   64
#define BM      128          // rows per block (8 waves x 16 rows)

__device__ inline unsigned cvtpk_bf16(float lo, float hi) {
    unsigned r;
    asm("v_cvt_pk_bf16_f32 %0, %1, %2" : "=v"(r) : "v"(lo), "v"(hi));
    return r;
}

// ---------------------------------------------------------------------------
// Kernel A: h = input @ W (fp32 compute), stored bf16 in MFMA B-frag layout:
// chunk[(kb*4+ct)*64 + l] (16B) = h[kb*32 + (l>>4)*8 + j][ct*16 + (l&15)]
// ---------------------------------------------------------------------------
__global__ __launch_bounds__(256) void dense_h(const float* __restrict__ inp,
                                               const float* __restrict__ W,
                                               short* __restrict__ hpack) {
    __shared__ float in_lds[64][64];
    __shared__ float wt_lds[64][68];
    const int t = threadIdx.x;
    const int blk = blockIdx.x;

#pragma unroll
    for (int i = 0; i < 4; ++i) {
        int n = i * 256 + t; int row = n >> 4; int c = n & 15;
        f32x4 v = *(const f32x4*)(inp + (size_t)(blk * 64 + row) * 64 + c * 4);
        *(f32x4*)(&in_lds[row][c * 4]) = v;
    }
#pragma unroll
    for (int i = 0; i < 4; ++i) {
        int n = i * 256 + t; int k = n >> 4; int c = n & 15;
        f32x4 v = *(const f32x4*)(W + k * 64 + c * 4);
        wt_lds[c * 4 + 0][k] = v.x; wt_lds[c * 4 + 1][k] = v.y;
        wt_lds[c * 4 + 2][k] = v.z; wt_lds[c * 4 + 3][k] = v.w;
    }
    __syncthreads();

#pragma unroll
    for (int cc = 0; cc < 2; ++cc) {
        int c = cc * 256 + t;
        int kbL = c >> 8; int ct = (c >> 6) & 3; int l = c & 63;
        int f  = ct * 16 + (l & 15);
        int r0 = kbL * 32 + (l >> 4) * 8;
        float acc[8] = {0, 0, 0, 0, 0, 0, 0, 0};
        for (int k = 0; k < 64; k += 4) {
            f32x4 wv = *(const f32x4*)(&wt_lds[f][k]);
#pragma unroll
            for (int j = 0; j < 8; ++j) {
                f32x4 iv = *(const f32x4*)(&in_lds[r0 + j][k]);
                acc[j] += iv.x * wv.x + iv.y * wv.y + iv.z * wv.z + iv.w * wv.w;
            }
        }
        u32x4 w4 = {cvtpk_bf16(acc[0], acc[1]), cvtpk_bf16(acc[2], acc[3]),
                    cvtpk_bf16(acc[4], acc[5]), cvtpk_bf16(acc[6], acc[7])};
        int kb = blk * 2 + kbL;
        *(u32x4*)(hpack + ((size_t)(kb * 4 + ct) * 64 + l) * 8) = w4;
    }
}

// ---------------------------------------------------------------------------
// Kernel B: partial[sp] = adj[:, k-range] @ h[k-range, :]
// R0 structure EXACTLY (block-wide coalesced LDS staging, XOR swizzle, raw
// s_barrier + lgkmcnt(0), inline B loads in the MFMA phase, 1-deep A
// prefetch). Changes vs R0: BM 64->128 (512 thr, 8 waves; halves hp
// re-read traffic) + nontemporal on adj (evict-first: keep 2MB hp
// L2-resident instead of letting the adj stream thrash it).
// ---------------------------------------------------------------------------
__global__ __launch_bounds__(512, 4) void spmm_adj(const float* __restrict__ adj,
                                                   const short* __restrict__ hp,
                                                   float* __restrict__ out,
                                                   int kspan) {
    const int rb = blockIdx.x;
    const int sp = blockIdx.y;
    const int k0 = sp * kspan;
    const int iters = kspan >> 6;          // K-step 64
    const int t  = threadIdx.x;
    const int wv = t >> 6;                 // 0..7
    const int ln = t & 63;

    __shared__ short At[2][BM * 64];       // bf16, XOR-swizzled, 16KB each

    const size_t rowbase = (size_t)(rb * BM) * N_NODES;
    const int srow = t >> 4;               // 0..31 staging row group
    const int scol = t & 15;               // 16B chunk within 256B row

    auto ldA = [&](int tt, f32x4* rv) {    // BM x 64 fp32 tile, 256B/row over 16 lanes
        const float* base = adj + rowbase + (size_t)(k0 + tt * 64);
#pragma unroll
        for (int i = 0; i < 4; ++i) {
            int row = i * 32 + srow;
            rv[i] = __builtin_nontemporal_load(
                (const f32x4*)(base + (size_t)row * N_NODES + scol * 4));
        }
    };
    auto stA = [&](int buf, const f32x4* rv) {
#pragma unroll
        for (int i = 0; i < 4; ++i) {
            int row = i * 32 + srow;
            u32x2 w = {cvtpk_bf16(rv[i].x, rv[i].y), cvtpk_bf16(rv[i].z, rv[i].w)};
            int byte = row * 128 + ((scol * 8) ^ ((row & 7) << 4));
            *(u32x2*)((char*)At[buf] + byte) = w;
        }
    };

    f32x4 acc[4] = {{0,0,0,0},{0,0,0,0},{0,0,0,0},{0,0,0,0}};
    const int abase = (wv * 16 + (ln & 15)) * 128;
    const int aswz  = (ln & 7) << 4;
    const int koff  = (ln >> 4) * 16;

    f32x4 rv[4];
    ldA(0, rv);
    stA(0, rv);

    for (int tt = 0; tt < iters; ++tt) {
        const int cur = tt & 1;
        const bool more = (tt + 1 < iters);
        if (more) ldA(tt + 1, rv);                     // prefetch next A tile
        asm volatile("s_waitcnt lgkmcnt(0)" ::: "memory");
        __builtin_amdgcn_s_barrier();                  // raw barrier: no vmcnt drain
#pragma unroll
        for (int ks2 = 0; ks2 < 2; ++ks2) {
            bf16x8 a = *(const bf16x8*)((const char*)At[cur] + abase + ((ks2 * 64 + koff) ^ aswz));
            const short* hbase = hp + ((size_t)((k0 >> 5) + tt * 2 + ks2) * 4) * 512;
#pragma unroll
            for (int ct = 0; ct < 4; ++ct) {
                bf16x8 b = *(const bf16x8*)(hbase + ct * 512 + ln * 8);   // L2-hot
                acc[ct] = __builtin_amdgcn_mfma_f32_16x16x32_bf16(a, b, acc[ct], 0, 0, 0);
            }
        }
        if (more) stA(cur ^ 1, rv);
    }

    // epilogue: C layout col=lane&15, row=(lane>>4)*4+j
    float* o = out + (size_t)sp * ((size_t)N_NODES * F_DIM);
    const int orow0 = rb * BM + wv * 16 + (ln >> 4) * 4;
    const int col   = ln & 15;
#pragma unroll
    for (int ct = 0; ct < 4; ++ct)
#pragma unroll
        for (int j = 0; j < 4; ++j)
            o[(size_t)(orow0 + j) * F_DIM + ct * 16 + col] = acc[ct][j];
}

// ---------------------------------------------------------------------------
// Kernel C: out = sum_i partial[i] + bias
// ---------------------------------------------------------------------------
__global__ __launch_bounds__(256) void reduce_add(const float* __restrict__ part,
                                                  const float* __restrict__ bias,
                                                  float* __restrict__ out, int nsp) {
    int g = blockIdx.x * 256 + threadIdx.x;
    f32x4 s = {0, 0, 0, 0};
    for (int i = 0; i < nsp; ++i)
        s += *(const f32x4*)(part + (size_t)i * ((size_t)N_NODES * F_DIM) + (size_t)g * 4);
    f32x4 bv = *(const f32x4*)(bias + ((g * 4) & 63));
    *(f32x4*)(out + (size_t)g * 4) = s + bv;
}

extern "C" void kernel_launch(void* const* d_in, const int* in_sizes, int n_in,
                              void* d_out, int out_size, void* d_ws, size_t ws_size,
                              hipStream_t stream) {
    const float* inp = (const float*)d_in[0];
    const float* adj = (const float*)d_in[1];
    const float* W   = (const float*)d_in[2];
    const float* b   = (const float*)d_in[3];
    float* out = (float*)d_out;

    char*  ws = (char*)d_ws;
    const size_t HP = (size_t)N_NODES * F_DIM * sizeof(short);   // 2 MB packed bf16 h
    short* hpack = (short*)ws;
    float* partial = (float*)(ws + HP);
    const size_t P1 = (size_t)N_NODES * F_DIM * sizeof(float);   // 4 MB per partial

    dense_h<<<N_NODES / 64, 256, 0, stream>>>(inp, W, hpack);

    if (ws_size >= HP + 4 * P1) {
        dim3 g(N_NODES / BM, 4);           // 512 blocks = 2/CU, one residency round
        spmm_adj<<<g, 512, 0, stream>>>(adj, hpack, partial, N_NODES / 4);
        reduce_add<<<(N_NODES * F_DIM) / 1024, 256, 0, stream>>>(partial, b, out, 4);
    } else if (ws_size >= HP + P1) {
        dim3 g(N_NODES / BM, 1);
        spmm_adj<<<g, 512, 0, stream>>>(adj, hpack, partial, N_NODES);
        reduce_add<<<(N_NODES * F_DIM) / 1024, 256, 0, stream>>>(partial, b, out, 1);
    } else {
        dim3 g(N_NODES / BM, 1);
        spmm_adj<<<g, 512, 0, stream>>>(adj, hpack, out, N_NODES);
        reduce_add<<<(N_NODES * F_DIM) / 1024, 256, 0, stream>>>(out, b, out, 1);
    }
}